// Round 2
// baseline (564.909 us; speedup 1.0000x reference)
//
#include <hip/hip_runtime.h>

#define NN 100000
#define NE 1200000
#define DD 64
#define EPS 1e-5f

// ---------------- degree histogram (in-degree by dst) ----------------
__global__ __launch_bounds__(256) void k_deg(const int* __restrict__ dst,
                                             int* __restrict__ cnt, int e) {
    int i = blockIdx.x * 256 + threadIdx.x;
    if (i < e) atomicAdd(&cnt[dst[i]], 1);
}

// cnt -> dinv = rsqrt(cnt+1), in place (int buffer reused as float)
__global__ __launch_bounds__(256) void k_dinv(int* __restrict__ c, int n) {
    int i = blockIdx.x * 256 + threadIdx.x;
    if (i < n) {
        float v = rsqrtf((float)c[i] + 1.0f);
        ((float*)c)[i] = v;
    }
}

// ---------------- hierarchical exclusive scan of counts -> offsets ----------------
__global__ __launch_bounds__(512) void k_scan1(const int* __restrict__ cnt,
                                               int* __restrict__ out,
                                               int* __restrict__ bsum, int n) {
    __shared__ int s[512];
    int t = threadIdx.x;
    int i = blockIdx.x * 512 + t;
    int v = (i < n) ? cnt[i] : 0;
    s[t] = v;
    __syncthreads();
    for (int off = 1; off < 512; off <<= 1) {
        int u = (t >= off) ? s[t - off] : 0;
        __syncthreads();
        s[t] += u;
        __syncthreads();
    }
    if (i < n) out[i] = s[t] - v;          // block-local exclusive
    if (t == 511) bsum[blockIdx.x] = s[511];
}

__global__ __launch_bounds__(256) void k_scan2(int* __restrict__ bsum, int nb) {
    __shared__ int s[256];
    int t = threadIdx.x;
    int v = (t < nb) ? bsum[t] : 0;
    s[t] = v;
    __syncthreads();
    for (int off = 1; off < 256; off <<= 1) {
        int u = (t >= off) ? s[t - off] : 0;
        __syncthreads();
        s[t] += u;
        __syncthreads();
    }
    if (t < nb) bsum[t] = s[t] - v;        // exclusive scan of block sums
}

__global__ __launch_bounds__(512) void k_scan3(int* __restrict__ out,
                                               const int* __restrict__ bsum,
                                               int n, int e) {
    int i = blockIdx.x * 512 + threadIdx.x;
    if (i < n) out[i] += bsum[blockIdx.x];
    if (i == 0) out[n] = e;                // total = E always
}

// ---------------- CSR fill: edges[pos] = (src, norm) ----------------
__global__ __launch_bounds__(256) void k_fill(const int* __restrict__ src,
                                              const int* __restrict__ dst,
                                              const float* __restrict__ dinv,
                                              int* __restrict__ cursor,
                                              int2* __restrict__ edges, int e) {
    int i = blockIdx.x * 256 + threadIdx.x;
    if (i < e) {
        int s = src[i], d = dst[i];
        int pos = atomicAdd(&cursor[d], 1);
        edges[pos] = make_int2(s, __float_as_int(dinv[s] * dinv[d]));
    }
}

// ---------------- GEMM: XW = X @ W  (N x 64) @ (64 x 64) ----------------
__global__ __launch_bounds__(256) void k_gemm(const float* __restrict__ X,
                                              const float* __restrict__ W,
                                              float* __restrict__ XW) {
    __shared__ float xs[32][64];
    int col = threadIdx.x & 63;
    int rg  = threadIdx.x >> 6;            // 0..3
    int row0 = blockIdx.x * 32;

    // W column in registers (reads coalesced across lanes, L1-hot across blocks)
    float w[64];
#pragma unroll
    for (int k = 0; k < 64; ++k) w[k] = W[k * 64 + col];

    // stage 32x64 x-tile (fully coalesced float4 loads)
    for (int i = threadIdx.x; i < 32 * 16; i += 256) {
        int r = i >> 4, c4 = i & 15;
        float4 v = ((const float4*)(X + (size_t)(row0 + r) * 64))[c4];
        ((float4*)&xs[r][0])[c4] = v;
    }
    __syncthreads();

    float acc[8];
#pragma unroll
    for (int r8 = 0; r8 < 8; ++r8) {
        int r = rg * 8 + r8;
        float a = 0.0f;
#pragma unroll
        for (int k = 0; k < 64; k += 4) {
            float4 xv = *((const float4*)&xs[r][k]);   // broadcast across wave
            a += xv.x * w[k] + xv.y * w[k + 1] + xv.z * w[k + 2] + xv.w * w[k + 3];
        }
        acc[r8] = a;
    }
#pragma unroll
    for (int r8 = 0; r8 < 8; ++r8)
        XW[(size_t)(row0 + rg * 8 + r8) * 64 + col] = acc[r8];
}

// ---------------- aggregation: gather over CSR, + self-loop term ----------------
__global__ __launch_bounds__(256) void k_agg(const float* __restrict__ XW,
                                             const int* __restrict__ off,
                                             const int2* __restrict__ edges,
                                             const float* __restrict__ dinv,
                                             float* __restrict__ out) {
    int node = blockIdx.x * 4 + (threadIdx.x >> 6);
    int lane = threadIdx.x & 63;
    float di = dinv[node];
    float acc = di * di * XW[(size_t)node * 64 + lane];
    int e0 = off[node], e1 = off[node + 1];
    for (int e = e0; e < e1; ++e) {
        int2 p = edges[e];                 // wave-uniform 8B load
        acc += __int_as_float(p.y) * XW[(size_t)p.x * 64 + lane];
    }
    out[(size_t)node * 64 + lane] = acc;
}

// ---------------- BN stats: column sums and sumsq ----------------
__global__ __launch_bounds__(256) void k_stats(const float* __restrict__ X,
                                               float* __restrict__ stats, int n) {
    __shared__ float ls[4][64], lq[4][64];
    int lane = threadIdx.x & 63, rg = threadIdx.x >> 6;
    float s = 0.0f, sq = 0.0f;
    for (int r = blockIdx.x * 4 + rg; r < n; r += gridDim.x * 4) {
        float v = X[(size_t)r * 64 + lane];
        s += v; sq += v * v;
    }
    ls[rg][lane] = s; lq[rg][lane] = sq;
    __syncthreads();
    if (rg == 0) {
        s  = ls[0][lane] + ls[1][lane] + ls[2][lane] + ls[3][lane];
        sq = lq[0][lane] + lq[1][lane] + lq[2][lane] + lq[3][lane];
        atomicAdd(&stats[lane], s);
        atomicAdd(&stats[64 + lane], sq);
    }
}

// ---------------- BN apply + leaky_relu (in place) ----------------
__global__ __launch_bounds__(256) void k_bnact(float* __restrict__ X,
                                               const float* __restrict__ stats,
                                               const float* __restrict__ gamma,
                                               const float* __restrict__ beta,
                                               int n) {
    int lane = threadIdx.x & 63, rg = threadIdx.x >> 6;
    float inv_n = 1.0f / (float)n;
    float mu  = stats[lane] * inv_n;
    float var = stats[64 + lane] * inv_n - mu * mu;
    float sc  = gamma[lane] * rsqrtf(var + EPS);
    float sh  = beta[lane] - sc * mu;
    for (int r = blockIdx.x * 4 + rg; r < n; r += gridDim.x * 4) {
        float v = X[(size_t)r * 64 + lane];
        v = sc * v + sh;
        X[(size_t)r * 64 + lane] = fmaxf(v, 0.01f * v);
    }
}

extern "C" void kernel_launch(void* const* d_in, const int* in_sizes, int n_in,
                              void* d_out, int out_size, void* d_ws, size_t ws_size,
                              hipStream_t stream) {
    const float* x   = (const float*)d_in[0];
    const int*   ei  = (const int*)d_in[1];
    const int*   src = ei;
    const int*   dst = ei + NE;
    const float* W1  = (const float*)d_in[2];
    const float* g1  = (const float*)d_in[4];
    const float* be1 = (const float*)d_in[5];
    const float* W2  = (const float*)d_in[6];
    const float* g2  = (const float*)d_in[8];
    const float* be2 = (const float*)d_in[9];
    float* out = (float*)d_out;

    char* ws = (char*)d_ws;
    size_t p = 0;
    auto alloc = [&](size_t bytes) {
        size_t o = p;
        p = (p + bytes + 255) & ~(size_t)255;
        return o;
    };
    int*   cntdinv = (int*)(ws + alloc((size_t)NN * 4));        // counts, then dinv
    int*   off     = (int*)(ws + alloc((size_t)(NN + 1) * 4));
    int*   cur     = (int*)(ws + alloc((size_t)NN * 4));
    int*   bsum    = (int*)(ws + alloc(1024));
    int2*  edges   = (int2*)(ws + alloc((size_t)NE * 8));
    float* stats   = (float*)(ws + alloc(1024));                // 128 per layer
    float* A       = (float*)(ws + alloc((size_t)NN * DD * 4)); // xw
    float* B       = (float*)(ws + alloc((size_t)NN * DD * 4)); // h1
    (void)ws_size; (void)in_sizes; (void)n_in; (void)out_size;

    float* dinv = (float*)cntdinv;

    hipMemsetAsync(cntdinv, 0, (size_t)NN * 4, stream);
    hipMemsetAsync(stats, 0, 1024, stream);

    k_deg<<<(NE + 255) / 256, 256, 0, stream>>>(dst, cntdinv, NE);

    int nb = (NN + 511) / 512;  // 196
    k_scan1<<<nb, 512, 0, stream>>>(cntdinv, off, bsum, NN);
    k_scan2<<<1, 256, 0, stream>>>(bsum, nb);
    k_scan3<<<nb, 512, 0, stream>>>(off, bsum, NN, NE);

    k_dinv<<<(NN + 255) / 256, 256, 0, stream>>>(cntdinv, NN);

    hipMemcpyAsync(cur, off, (size_t)NN * 4, hipMemcpyDeviceToDevice, stream);
    k_fill<<<(NE + 255) / 256, 256, 0, stream>>>(src, dst, dinv, cur, edges, NE);

    // ---- layer 1 ----
    k_gemm<<<NN / 32, 256, 0, stream>>>(x, W1, A);
    k_agg<<<NN / 4, 256, 0, stream>>>(A, off, edges, dinv, B);
    k_stats<<<512, 256, 0, stream>>>(B, stats, NN);
    k_bnact<<<1024, 256, 0, stream>>>(B, stats, g1, be1, NN);

    // ---- layer 2 ----
    k_gemm<<<NN / 32, 256, 0, stream>>>(B, W2, A);
    k_agg<<<NN / 4, 256, 0, stream>>>(A, off, edges, dinv, out);
    k_stats<<<512, 256, 0, stream>>>(out, stats + 128, NN);
    k_bnact<<<1024, 256, 0, stream>>>(out, stats + 128, g2, be2, NN);
}

// Round 3
// 410.584 us; speedup vs baseline: 1.3759x; 1.3759x over previous
//
#include <hip/hip_runtime.h>

#define NN 100000
#define NE 1200000
#define DD 64
#define EPS 1e-5f

// ---------------- degree histogram (in-degree by dst) ----------------
__global__ __launch_bounds__(256) void k_deg(const int* __restrict__ dst,
                                             int* __restrict__ cnt, int e) {
    int i = blockIdx.x * 256 + threadIdx.x;
    if (i < e) atomicAdd(&cnt[dst[i]], 1);
}

// cnt -> dinv = rsqrt(cnt+1), in place (int buffer reused as float)
__global__ __launch_bounds__(256) void k_dinv(int* __restrict__ c, int n) {
    int i = blockIdx.x * 256 + threadIdx.x;
    if (i < n) {
        float v = rsqrtf((float)c[i] + 1.0f);
        ((float*)c)[i] = v;
    }
}

// ---------------- hierarchical exclusive scan of counts -> offsets ----------------
__global__ __launch_bounds__(512) void k_scan1(const int* __restrict__ cnt,
                                               int* __restrict__ out,
                                               int* __restrict__ bsum, int n) {
    __shared__ int s[512];
    int t = threadIdx.x;
    int i = blockIdx.x * 512 + t;
    int v = (i < n) ? cnt[i] : 0;
    s[t] = v;
    __syncthreads();
    for (int off = 1; off < 512; off <<= 1) {
        int u = (t >= off) ? s[t - off] : 0;
        __syncthreads();
        s[t] += u;
        __syncthreads();
    }
    if (i < n) out[i] = s[t] - v;          // block-local exclusive
    if (t == 511) bsum[blockIdx.x] = s[511];
}

__global__ __launch_bounds__(256) void k_scan2(int* __restrict__ bsum, int nb) {
    __shared__ int s[256];
    int t = threadIdx.x;
    int v = (t < nb) ? bsum[t] : 0;
    s[t] = v;
    __syncthreads();
    for (int off = 1; off < 256; off <<= 1) {
        int u = (t >= off) ? s[t - off] : 0;
        __syncthreads();
        s[t] += u;
        __syncthreads();
    }
    if (t < nb) bsum[t] = s[t] - v;        // exclusive scan of block sums
}

__global__ __launch_bounds__(512) void k_scan3(int* __restrict__ out,
                                               const int* __restrict__ bsum,
                                               int n, int e) {
    int i = blockIdx.x * 512 + threadIdx.x;
    if (i < n) out[i] += bsum[blockIdx.x];
    if (i == 0) out[n] = e;                // total = E always
}

// ---------------- CSR fill: edges[pos] = (src, norm) ----------------
__global__ __launch_bounds__(256) void k_fill(const int* __restrict__ src,
                                              const int* __restrict__ dst,
                                              const float* __restrict__ dinv,
                                              int* __restrict__ cursor,
                                              int2* __restrict__ edges, int e) {
    int i = blockIdx.x * 256 + threadIdx.x;
    if (i < e) {
        int s = src[i], d = dst[i];
        int pos = atomicAdd(&cursor[d], 1);
        edges[pos] = make_int2(s, __float_as_int(dinv[s] * dinv[d]));
    }
}

// ---------------- GEMM: XW = X @ W, optionally fusing BN-affine+leaky on X ----------------
template <bool BN>
__global__ __launch_bounds__(256) void k_gemm(const float* __restrict__ X,
                                              const float* __restrict__ W,
                                              float* __restrict__ XW,
                                              const float* __restrict__ stats,
                                              const float* __restrict__ gamma,
                                              const float* __restrict__ beta) {
    __shared__ float xs[32][64];
    __shared__ float sc_s[64], sh_s[64];
    int col = threadIdx.x & 63;
    int rg  = threadIdx.x >> 6;            // 0..3
    int row0 = blockIdx.x * 32;

    if (BN) {
        if (threadIdx.x < 64) {
            const float inv_n = 1.0f / (float)NN;
            float mu  = stats[threadIdx.x] * inv_n;
            float var = stats[64 + threadIdx.x] * inv_n - mu * mu;
            float sc  = gamma[threadIdx.x] * rsqrtf(var + EPS);
            sc_s[threadIdx.x] = sc;
            sh_s[threadIdx.x] = beta[threadIdx.x] - sc * mu;
        }
        __syncthreads();
    }

    // W column in registers (reads coalesced across lanes, L2-hot across blocks)
    float w[64];
#pragma unroll
    for (int k = 0; k < 64; ++k) w[k] = W[k * 64 + col];

    // stage 32x64 x-tile (fully coalesced float4 loads), optional BN+leaky
    for (int i = threadIdx.x; i < 32 * 16; i += 256) {
        int r = i >> 4, c4 = i & 15;
        float4 v = ((const float4*)(X + (size_t)(row0 + r) * 64))[c4];
        if (BN) {
            float4 s4 = ((const float4*)sc_s)[c4];
            float4 h4 = ((const float4*)sh_s)[c4];
            v.x = s4.x * v.x + h4.x; v.x = fmaxf(v.x, 0.01f * v.x);
            v.y = s4.y * v.y + h4.y; v.y = fmaxf(v.y, 0.01f * v.y);
            v.z = s4.z * v.z + h4.z; v.z = fmaxf(v.z, 0.01f * v.z);
            v.w = s4.w * v.w + h4.w; v.w = fmaxf(v.w, 0.01f * v.w);
        }
        ((float4*)&xs[r][0])[c4] = v;
    }
    __syncthreads();

    float acc[8];
#pragma unroll
    for (int r8 = 0; r8 < 8; ++r8) {
        int r = rg * 8 + r8;
        float a = 0.0f;
#pragma unroll
        for (int k = 0; k < 64; k += 4) {
            float4 xv = *((const float4*)&xs[r][k]);   // broadcast across wave
            a += xv.x * w[k] + xv.y * w[k + 1] + xv.z * w[k + 2] + xv.w * w[k + 3];
        }
        acc[r8] = a;
    }
#pragma unroll
    for (int r8 = 0; r8 < 8; ++r8)
        XW[(size_t)(row0 + rg * 8 + r8) * 64 + col] = acc[r8];
}

// ---------------- aggregation: gather over CSR with 4 edge-groups x float4 lanes ----------------
// Wave = 1 node. 4 groups of 16 lanes; each lane holds float4 (quad = lane&15).
// Group g walks edges e0+g, e0+g+4, ... ; 2x unrolled with dual accumulators
// -> up to 8 independent 256B row-gathers in flight per wave.
__global__ __launch_bounds__(256) void k_agg(const float* __restrict__ XW,
                                             const int* __restrict__ off,
                                             const int2* __restrict__ edges,
                                             const float* __restrict__ dinv,
                                             float* __restrict__ out) {
    const float4* __restrict__ XW4 = (const float4*)XW;
    int node = blockIdx.x * 4 + (threadIdx.x >> 6);
    int lane = threadIdx.x & 63;
    int grp  = lane >> 4;                  // 0..3
    int sub  = lane & 15;                  // float4 slot within row

    float di = dinv[node];
    float sl = (grp == 0) ? di * di : 0.0f;
    float4 row = XW4[(size_t)node * 16 + sub];
    float4 a0 = make_float4(sl * row.x, sl * row.y, sl * row.z, sl * row.w);
    float4 a1 = make_float4(0.f, 0.f, 0.f, 0.f);

    int e0 = off[node], e1 = off[node + 1];
    int e = e0 + grp;
    for (; e + 4 < e1; e += 8) {
        int2 p0 = edges[e];
        int2 p1 = edges[e + 4];
        float n0 = __int_as_float(p0.y);
        float n1 = __int_as_float(p1.y);
        float4 r0 = XW4[(size_t)p0.x * 16 + sub];
        float4 r1 = XW4[(size_t)p1.x * 16 + sub];
        a0.x += n0 * r0.x; a0.y += n0 * r0.y; a0.z += n0 * r0.z; a0.w += n0 * r0.w;
        a1.x += n1 * r1.x; a1.y += n1 * r1.y; a1.z += n1 * r1.z; a1.w += n1 * r1.w;
    }
    if (e < e1) {
        int2 p0 = edges[e];
        float n0 = __int_as_float(p0.y);
        float4 r0 = XW4[(size_t)p0.x * 16 + sub];
        a0.x += n0 * r0.x; a0.y += n0 * r0.y; a0.z += n0 * r0.z; a0.w += n0 * r0.w;
    }
    a0.x += a1.x; a0.y += a1.y; a0.z += a1.z; a0.w += a1.w;

    // reduce across the 4 groups (lane bits 4,5)
#pragma unroll
    for (int m = 16; m <= 32; m <<= 1) {
        a0.x += __shfl_xor(a0.x, m);
        a0.y += __shfl_xor(a0.y, m);
        a0.z += __shfl_xor(a0.z, m);
        a0.w += __shfl_xor(a0.w, m);
    }
    if (grp == 0)
        ((float4*)out)[(size_t)node * 16 + sub] = a0;
}

// ---------------- BN stats: column sums and sumsq ----------------
__global__ __launch_bounds__(256) void k_stats(const float* __restrict__ X,
                                               float* __restrict__ stats, int n) {
    __shared__ float ls[4][64], lq[4][64];
    int lane = threadIdx.x & 63, rg = threadIdx.x >> 6;
    float s = 0.0f, sq = 0.0f;
    for (int r = blockIdx.x * 4 + rg; r < n; r += gridDim.x * 4) {
        float v = X[(size_t)r * 64 + lane];
        s += v; sq += v * v;
    }
    ls[rg][lane] = s; lq[rg][lane] = sq;
    __syncthreads();
    if (rg == 0) {
        s  = ls[0][lane] + ls[1][lane] + ls[2][lane] + ls[3][lane];
        sq = lq[0][lane] + lq[1][lane] + lq[2][lane] + lq[3][lane];
        atomicAdd(&stats[lane], s);
        atomicAdd(&stats[64 + lane], sq);
    }
}

// ---------------- BN apply + leaky_relu (out-of-place) ----------------
__global__ __launch_bounds__(256) void k_bnact(const float* __restrict__ X,
                                               float* __restrict__ Y,
                                               const float* __restrict__ stats,
                                               const float* __restrict__ gamma,
                                               const float* __restrict__ beta,
                                               int n) {
    int lane = threadIdx.x & 63, rg = threadIdx.x >> 6;
    float inv_n = 1.0f / (float)n;
    float mu  = stats[lane] * inv_n;
    float var = stats[64 + lane] * inv_n - mu * mu;
    float sc  = gamma[lane] * rsqrtf(var + EPS);
    float sh  = beta[lane] - sc * mu;
    for (int r = blockIdx.x * 4 + rg; r < n; r += gridDim.x * 4) {
        float v = X[(size_t)r * 64 + lane];
        v = sc * v + sh;
        Y[(size_t)r * 64 + lane] = fmaxf(v, 0.01f * v);
    }
}

extern "C" void kernel_launch(void* const* d_in, const int* in_sizes, int n_in,
                              void* d_out, int out_size, void* d_ws, size_t ws_size,
                              hipStream_t stream) {
    const float* x   = (const float*)d_in[0];
    const int*   ei  = (const int*)d_in[1];
    const int*   src = ei;
    const int*   dst = ei + NE;
    const float* W1  = (const float*)d_in[2];
    const float* g1  = (const float*)d_in[4];
    const float* be1 = (const float*)d_in[5];
    const float* W2  = (const float*)d_in[6];
    const float* g2  = (const float*)d_in[8];
    const float* be2 = (const float*)d_in[9];
    float* out = (float*)d_out;

    char* ws = (char*)d_ws;
    size_t p = 0;
    auto alloc = [&](size_t bytes) {
        size_t o = p;
        p = (p + bytes + 255) & ~(size_t)255;
        return o;
    };
    int*   cntdinv = (int*)(ws + alloc((size_t)NN * 4));        // counts, then dinv
    int*   off     = (int*)(ws + alloc((size_t)(NN + 1) * 4));
    int*   cur     = (int*)(ws + alloc((size_t)NN * 4));
    int*   bsum    = (int*)(ws + alloc(1024));
    int2*  edges   = (int2*)(ws + alloc((size_t)NE * 8));
    float* stats   = (float*)(ws + alloc(1024));                // 128 per layer
    float* A       = (float*)(ws + alloc((size_t)NN * DD * 4)); // xw / h2 staging
    float* B       = (float*)(ws + alloc((size_t)NN * DD * 4)); // raw agg1
    (void)ws_size; (void)in_sizes; (void)n_in; (void)out_size;

    float* dinv = (float*)cntdinv;

    hipMemsetAsync(cntdinv, 0, (size_t)NN * 4, stream);
    hipMemsetAsync(stats, 0, 1024, stream);

    k_deg<<<(NE + 255) / 256, 256, 0, stream>>>(dst, cntdinv, NE);

    int nb = (NN + 511) / 512;  // 196
    k_scan1<<<nb, 512, 0, stream>>>(cntdinv, off, bsum, NN);
    k_scan2<<<1, 256, 0, stream>>>(bsum, nb);
    k_scan3<<<nb, 512, 0, stream>>>(off, bsum, NN, NE);

    k_dinv<<<(NN + 255) / 256, 256, 0, stream>>>(cntdinv, NN);

    hipMemcpyAsync(cur, off, (size_t)NN * 4, hipMemcpyDeviceToDevice, stream);
    k_fill<<<(NE + 255) / 256, 256, 0, stream>>>(src, dst, dinv, cur, edges, NE);

    // ---- layer 1 ----
    k_gemm<false><<<NN / 32, 256, 0, stream>>>(x, W1, A, nullptr, nullptr, nullptr);
    k_agg<<<NN / 4, 256, 0, stream>>>(A, off, edges, dinv, B);      // B = raw agg1
    k_stats<<<512, 256, 0, stream>>>(B, stats, NN);

    // ---- layer 2 (BN1+leaky fused into gemm's x-load) ----
    k_gemm<true><<<NN / 32, 256, 0, stream>>>(B, W2, A, stats, g1, be1);
    k_agg<<<NN / 4, 256, 0, stream>>>(A, off, edges, dinv, B);      // B = raw agg2
    k_stats<<<512, 256, 0, stream>>>(B, stats + 128, NN);
    k_bnact<<<1024, 256, 0, stream>>>(B, out, stats + 128, g2, be2, NN);
}